// Round 1
// baseline (264.899 us; speedup 1.0000x reference)
//
#include <hip/hip_runtime.h>
#include <limits.h>
#include <math.h>
#include <stdint.h>

// Problem constants (fixed by setup_inputs): x[128][262144] fp32, topk=5.
#define BROWS 128
#define NCOLS (256 * 32 * 32)        // 262144 elements per row
#define K 5
#define BPR 16                       // groups (blocks) per row -> 2048 blocks
#define TPB 256
#define CHUNK (NCOLS / BPR)          // 16384 elements per group
#define F4T (CHUNK / 4 / TPB)        // 16 float4 per thread
#define NW (TPB / 64)                // waves per block

typedef float v4f __attribute__((ext_vector_type(4)));

// ---- packed 64-bit candidate key: [sortable_f32 : 32][~index : 32] ----
// bigger key == better (value desc, then index asc) -> matches jax.lax.top_k.
__device__ __forceinline__ uint64_t make_key(float f, uint32_t idx) {
    uint32_t u = __float_as_uint(f);
    u = (u & 0x80000000u) ? ~u : (u | 0x80000000u);   // monotone fp32 -> u32
    return ((uint64_t)u << 32) | (uint32_t)(~idx);
}
__device__ __forceinline__ uint32_t key_idx(uint64_t k) { return ~(uint32_t)k; }
__device__ __forceinline__ float key_val(uint64_t k) {  // inverse of the monotone map
    uint32_t u = (uint32_t)(k >> 32);
    u = (u & 0x80000000u) ? (u & 0x7FFFFFFFu) : ~u;
    return __uint_as_float(u);
}

#define KEY_NEG_INF 0x007FFFFF00000000ULL  // make_key(-INFINITY, 0xFFFFFFFF)

__device__ __forceinline__ void insert5(uint64_t (&key)[K], uint64_t c) {
    if (c > key[K - 1]) {
        key[K - 1] = c;
#pragma unroll
        for (int s = K - 1; s > 0; --s) {
            if (key[s] > key[s - 1]) {
                uint64_t t = key[s]; key[s] = key[s - 1]; key[s - 1] = t;
            }
        }
    }
}

__device__ __forceinline__ void wave_reduce5(uint64_t (&key)[K]) {
#pragma unroll
    for (int off = 1; off < 64; off <<= 1) {
        uint64_t ok[K];
#pragma unroll
        for (int k = 0; k < K; ++k)
            ok[k] = __shfl_xor((unsigned long long)key[k], off, 64);
#pragma unroll
        for (int k = 0; k < K; ++k) insert5(key, ok[k]);
    }
}

// K1 (fused): single streaming pass. Per group-block: zero-fill out (nt stores),
// compute the block-local top-5 exactly (float fast-path guard, u64-key inserts
// on the rare >= hit), butterfly-reduce per wave, combine 4 waves via LDS, and
// emit 5 candidate keys. Per-row top-5 == top-5 of the 16 group top-5s, so no
// global threshold pass and no atomics are needed. x is read exactly once.
__global__ __launch_bounds__(TPB) void wta_pass(const float* __restrict__ x,
                                                float* __restrict__ out,
                                                uint64_t* __restrict__ cand) {
    const int gb  = blockIdx.x;
    const int row = gb / BPR;
    const int blk = gb % BPR;
    const size_t base = (size_t)gb * CHUNK;
    const float4* __restrict__ x4 = (const float4*)(x + base);
    v4f* __restrict__ o4 = (v4f*)(out + base);
    const int t = threadIdx.x;
    const v4f z = {0.f, 0.f, 0.f, 0.f};

    uint64_t key[K];
#pragma unroll
    for (int k = 0; k < K; ++k) key[k] = KEY_NEG_INF;
    float vth = -INFINITY;               // value of current 5th-best (fast-path guard)
    const uint32_t ebase = (uint32_t)blk * CHUNK;

#pragma unroll
    for (int h = 0; h < 2; ++h) {        // two half-batches of 8 for bounded VGPRs
        float4 r[F4T / 2];
#pragma unroll
        for (int j = 0; j < F4T / 2; ++j)
            r[j] = x4[t + (h * (F4T / 2) + j) * TPB];
#pragma unroll
        for (int j = 0; j < F4T / 2; ++j)
            __builtin_nontemporal_store(z, &o4[t + (h * (F4T / 2) + j) * TPB]);
#pragma unroll
        for (int j = 0; j < F4T / 2; ++j) {
            const float4 d = r[j];
            const float m = fmaxf(fmaxf(d.x, d.y), fmaxf(d.z, d.w));
            if (m >= vth) {              // rare after warm-up (~10 hits/thread total)
                const uint32_t e = ebase + (uint32_t)(t + (h * (F4T / 2) + j) * TPB) * 4u;
                const float vs[4] = {d.x, d.y, d.z, d.w};
#pragma unroll
                for (int c = 0; c < 4; ++c) insert5(key, make_key(vs[c], e + c));
                vth = key_val(key[K - 1]);
            }
        }
    }

    // wave-level exact top-5
    wave_reduce5(key);

    // block-level combine: 4 wave leaders -> LDS -> wave 0 reduces 20 keys
    __shared__ uint64_t sk[NW * K];
    const int lane = t & 63, w = t >> 6;
    if (lane == 0) {
#pragma unroll
        for (int k = 0; k < K; ++k) sk[w * K + k] = key[k];
    }
    __syncthreads();
    if (t < 64) {
        uint64_t fk[K];
#pragma unroll
        for (int k = 0; k < K; ++k) fk[k] = KEY_NEG_INF;
        if (t < NW * K) fk[0] = sk[t];   // stays sorted-desc: fk[0] >= NEG_INF
        wave_reduce5(fk);
        if (t == 0) {
#pragma unroll
            for (int k = 0; k < K; ++k)
                cand[((size_t)row * BPR + blk) * K + k] = fk[k];
        }
    }
}

// K2: per row, exact top-5 of the 80 fixed candidates, scatter five 1.0f stores.
__global__ __launch_bounds__(64) void wta_final(const uint64_t* __restrict__ cand,
                                                float* __restrict__ out) {
    const int row = blockIdx.x, lane = threadIdx.x;
    const uint64_t* __restrict__ c = cand + (size_t)row * BPR * K;

    uint64_t key[K];
#pragma unroll
    for (int k = 0; k < K; ++k) key[k] = KEY_NEG_INF;
#pragma unroll
    for (int i = 0; i < 2; ++i) {        // 80 candidates over 64 lanes
        const int j = i * 64 + lane;
        if (j < BPR * K) insert5(key, c[j]);
    }

    wave_reduce5(key);

    if (lane == 0) {
#pragma unroll
        for (int k = 0; k < K; ++k)
            if (key[k] != KEY_NEG_INF)
                out[(size_t)row * NCOLS + key_idx(key[k])] = 1.0f;
    }
}

extern "C" void kernel_launch(void* const* d_in, const int* in_sizes, int n_in,
                              void* d_out, int out_size, void* d_ws, size_t ws_size,
                              hipStream_t stream) {
    const float* x = (const float*)d_in[0];
    float* out = (float*)d_out;

    // ws layout: cand (128 * 16 * 5 u64 = 80 KiB)
    uint64_t* cand = (uint64_t*)d_ws;

    wta_pass<<<BROWS * BPR, TPB, 0, stream>>>(x, out, cand);
    wta_final<<<BROWS, 64, 0, stream>>>(cand, out);
}

// Round 2
// 250.662 us; speedup vs baseline: 1.0568x; 1.0568x over previous
//
#include <hip/hip_runtime.h>
#include <limits.h>
#include <math.h>
#include <stdint.h>

// Problem constants (fixed by setup_inputs): x[128][262144] fp32, topk=5.
#define BROWS 128
#define NCOLS (256 * 32 * 32)        // 262144 elements per row
#define K 5
#define BPR 32                       // groups (blocks) per row -> 4096 blocks
#define TPB 256
#define CHUNK (NCOLS / BPR)          // 8192 elements per group
#define F4T (CHUNK / 4 / TPB)        // 8 float4 per thread (32 VGPRs of data)
#define NW (TPB / 64)                // waves per block

typedef float v4f __attribute__((ext_vector_type(4)));

// ---- packed 64-bit candidate key: [sortable_f32 : 32][~index : 32] ----
// bigger key == better (value desc, then index asc) -> matches jax.lax.top_k.
__device__ __forceinline__ uint64_t make_key(float f, uint32_t idx) {
    uint32_t u = __float_as_uint(f);
    u = (u & 0x80000000u) ? ~u : (u | 0x80000000u);   // monotone fp32 -> u32
    return ((uint64_t)u << 32) | (uint32_t)(~idx);
}
__device__ __forceinline__ uint32_t key_idx(uint64_t k) { return ~(uint32_t)k; }

#define KEY_NEG_INF 0x007FFFFF00000000ULL  // make_key(-INFINITY, 0xFFFFFFFF)

__device__ __forceinline__ void insert5(uint64_t (&key)[K], uint64_t c) {
    if (c > key[K - 1]) {
        key[K - 1] = c;
#pragma unroll
        for (int s = K - 1; s > 0; --s) {
            if (key[s] > key[s - 1]) {
                uint64_t t = key[s]; key[s] = key[s - 1]; key[s - 1] = t;
            }
        }
    }
}

__device__ __forceinline__ void wave_reduce5(uint64_t (&key)[K]) {
#pragma unroll
    for (int off = 1; off < 64; off <<= 1) {
        uint64_t ok[K];
#pragma unroll
        for (int k = 0; k < K; ++k)
            ok[k] = __shfl_xor((unsigned long long)key[k], off, 64);
#pragma unroll
        for (int k = 0; k < K; ++k) insert5(key, ok[k]);
    }
}

// float top-5 insert (values only, for the wave threshold)
__device__ __forceinline__ void insert5f(float (&v)[K], float c) {
    if (c > v[K - 1]) {
        v[K - 1] = c;
#pragma unroll
        for (int s = K - 1; s > 0; --s) {
            if (v[s] > v[s - 1]) { float t = v[s]; v[s] = v[s - 1]; v[s - 1] = t; }
        }
    }
}

// K1 (fused, single read of x):
//  Phase A (branch-free): 8x float4 loads -> regs, nt zero-stores, per-f4 maxes,
//    thread max M. No conditionals, no loop-carried deps -> loads fully pipelined.
//  Threshold: wave butterfly top-5 of the 64 thread maxes; T = 5th. T is the min
//    of 5 actual elements => >=5 elements >= T => true wave-5th >= T (safe guard).
//  Phase B: guarded exact u64-key inserts against loop-invariant T over the
//    register-resident data (~5-8 survivors per 2048-elem wave).
//  Then wave reduce + 4-wave LDS combine -> 5 candidate keys per block.
__global__ __launch_bounds__(TPB) void wta_pass(const float* __restrict__ x,
                                                float* __restrict__ out,
                                                uint64_t* __restrict__ cand) {
    const int gb  = blockIdx.x;
    const int row = gb / BPR;
    const int blk = gb % BPR;
    const size_t base = (size_t)gb * CHUNK;
    const float4* __restrict__ x4 = (const float4*)(x + base);
    v4f* __restrict__ o4 = (v4f*)(out + base);
    const int t = threadIdx.x;
    const v4f z = {0.f, 0.f, 0.f, 0.f};

    // ---- Phase A: branch-free streaming ----
    float4 d[F4T];
#pragma unroll
    for (int j = 0; j < F4T; ++j) d[j] = x4[t + j * TPB];
#pragma unroll
    for (int j = 0; j < F4T; ++j)
        __builtin_nontemporal_store(z, &o4[t + j * TPB]);

    float mj[F4T];
#pragma unroll
    for (int j = 0; j < F4T; ++j)
        mj[j] = fmaxf(fmaxf(d[j].x, d[j].y), fmaxf(d[j].z, d[j].w));
    float M = -INFINITY;
#pragma unroll
    for (int j = 0; j < F4T; ++j) M = fmaxf(M, mj[j]);

    // ---- wave threshold: top-5 of the 64 thread maxes ----
    float v[K];
    v[0] = M;
#pragma unroll
    for (int k = 1; k < K; ++k) v[k] = -INFINITY;
#pragma unroll
    for (int off = 1; off < 64; off <<= 1) {
        float ov[K];
#pragma unroll
        for (int k = 0; k < K; ++k) ov[k] = __shfl_xor(v[k], off, 64);
#pragma unroll
        for (int k = 0; k < K; ++k) insert5f(v, ov[k]);
    }
    const float T = v[K - 1];            // wave-uniform, loop-invariant

    // ---- Phase B: rare exact inserts from registers ----
    uint64_t key[K];
#pragma unroll
    for (int k = 0; k < K; ++k) key[k] = KEY_NEG_INF;
    const uint32_t ebase = (uint32_t)blk * CHUNK;
#pragma unroll
    for (int j = 0; j < F4T; ++j) {
        if (mj[j] >= T) {                // ~5-8 hits per wave total
            const uint32_t e = ebase + (uint32_t)(t + j * TPB) * 4u;
            const float vs[4] = {d[j].x, d[j].y, d[j].z, d[j].w};
#pragma unroll
            for (int c = 0; c < 4; ++c)
                if (vs[c] >= T) insert5(key, make_key(vs[c], e + c));
        }
    }

    // wave-level exact top-5
    wave_reduce5(key);

    // block-level combine: 4 wave leaders -> LDS -> wave 0 reduces 20 keys
    __shared__ uint64_t sk[NW * K];
    const int lane = t & 63, w = t >> 6;
    if (lane == 0) {
#pragma unroll
        for (int k = 0; k < K; ++k) sk[w * K + k] = key[k];
    }
    __syncthreads();
    if (t < 64) {
        uint64_t fk[K];
#pragma unroll
        for (int k = 0; k < K; ++k) fk[k] = KEY_NEG_INF;
        if (t < NW * K) fk[0] = sk[t];   // stays sorted-desc: fk[0] >= NEG_INF
        wave_reduce5(fk);
        if (t == 0) {
#pragma unroll
            for (int k = 0; k < K; ++k)
                cand[((size_t)row * BPR + blk) * K + k] = fk[k];
        }
    }
}

// K2: per row, exact top-5 of the 160 fixed candidates, scatter five 1.0f stores.
__global__ __launch_bounds__(64) void wta_final(const uint64_t* __restrict__ cand,
                                                float* __restrict__ out) {
    const int row = blockIdx.x, lane = threadIdx.x;
    const uint64_t* __restrict__ c = cand + (size_t)row * BPR * K;

    uint64_t key[K];
#pragma unroll
    for (int k = 0; k < K; ++k) key[k] = KEY_NEG_INF;
#pragma unroll
    for (int i = 0; i < (BPR * K + 63) / 64; ++i) {   // 160 candidates over 64 lanes
        const int j = i * 64 + lane;
        if (j < BPR * K) insert5(key, c[j]);
    }

    wave_reduce5(key);

    if (lane == 0) {
#pragma unroll
        for (int k = 0; k < K; ++k)
            if (key[k] != KEY_NEG_INF)
                out[(size_t)row * NCOLS + key_idx(key[k])] = 1.0f;
    }
}

extern "C" void kernel_launch(void* const* d_in, const int* in_sizes, int n_in,
                              void* d_out, int out_size, void* d_ws, size_t ws_size,
                              hipStream_t stream) {
    const float* x = (const float*)d_in[0];
    float* out = (float*)d_out;

    // ws layout: cand (128 * 32 * 5 u64 = 160 KiB)
    uint64_t* cand = (uint64_t*)d_ws;

    wta_pass<<<BROWS * BPR, TPB, 0, stream>>>(x, out, cand);
    wta_final<<<BROWS, 64, 0, stream>>>(cand, out);
}

// Round 3
// 244.292 us; speedup vs baseline: 1.0844x; 1.0261x over previous
//
#include <hip/hip_runtime.h>
#include <limits.h>
#include <math.h>
#include <stdint.h>

// Problem constants (fixed by setup_inputs): x[128][262144] fp32, topk=5.
#define BROWS 128
#define NCOLS (256 * 32 * 32)        // 262144 elements per row
#define K 5
#define BPR 32                       // stream blocks per row -> 4096 blocks
#define TPB 256
#define CHUNK (NCOLS / BPR)          // 8192 elements per stream block
#define F4T (CHUNK / 4 / TPB)        // 8 float4 per thread
#define WPR (BPR * 4)                // wave-chunks per row = 128
#define NFLAG 16                     // flagged-chunk capacity (expect ~5)
#define CAP 256                      // candidate capacity (expect ~10)

typedef float v4f __attribute__((ext_vector_type(4)));

// ---- packed 64-bit candidate key: [sortable_f32 : 32][~index : 32] ----
// bigger key == better (value desc, then index asc) -> matches jax.lax.top_k.
__device__ __forceinline__ uint64_t make_key(float f, uint32_t idx) {
    uint32_t u = __float_as_uint(f);
    u = (u & 0x80000000u) ? ~u : (u | 0x80000000u);   // monotone fp32 -> u32
    return ((uint64_t)u << 32) | (uint32_t)(~idx);
}
__device__ __forceinline__ uint32_t key_idx(uint64_t k) { return ~(uint32_t)k; }

#define KEY_NEG_INF 0x007FFFFF00000000ULL  // make_key(-INFINITY, 0xFFFFFFFF)

__device__ __forceinline__ void insert5(uint64_t (&key)[K], uint64_t c) {
    if (c > key[K - 1]) {
        key[K - 1] = c;
#pragma unroll
        for (int s = K - 1; s > 0; --s) {
            if (key[s] > key[s - 1]) {
                uint64_t t = key[s]; key[s] = key[s - 1]; key[s - 1] = t;
            }
        }
    }
}

__device__ __forceinline__ void wave_reduce5(uint64_t (&key)[K]) {
#pragma unroll
    for (int off = 1; off < 64; off <<= 1) {
        uint64_t ok[K];
#pragma unroll
        for (int k = 0; k < K; ++k)
            ok[k] = __shfl_xor((unsigned long long)key[k], off, 64);
#pragma unroll
        for (int k = 0; k < K; ++k) insert5(key, ok[k]);
    }
}

// float top-5 insert (values only, for the threshold)
__device__ __forceinline__ void insert5f(float (&v)[K], float c) {
    if (c > v[K - 1]) {
        v[K - 1] = c;
#pragma unroll
        for (int s = K - 1; s > 0; --s) {
            if (v[s] > v[s - 1]) { float t = v[s]; v[s] = v[s - 1]; v[s - 1] = t; }
        }
    }
}

// K1: near-pure streaming pass. Load 8 float4 -> nt zero-store 8 -> thread max
// -> wave butterfly MAX (6 shfl+fmax) -> one scalar store per wave. No LDS, no
// syncthreads, no branches, no 64-bit shuffles: nothing to stall the stream.
__global__ __launch_bounds__(TPB) void wta_stream(const float* __restrict__ x,
                                                  float* __restrict__ out,
                                                  float* __restrict__ wmax) {
    const int gb = blockIdx.x;
    const size_t base = (size_t)gb * CHUNK;
    const float4* __restrict__ x4 = (const float4*)(x + base);
    v4f* __restrict__ o4 = (v4f*)(out + base);
    const int t = threadIdx.x;
    const v4f z = {0.f, 0.f, 0.f, 0.f};

    float4 d[F4T];
#pragma unroll
    for (int j = 0; j < F4T; ++j) d[j] = x4[t + j * TPB];
#pragma unroll
    for (int j = 0; j < F4T; ++j)
        __builtin_nontemporal_store(z, &o4[t + j * TPB]);

    float M = -INFINITY;
#pragma unroll
    for (int j = 0; j < F4T; ++j)
        M = fmaxf(M, fmaxf(fmaxf(d[j].x, d[j].y), fmaxf(d[j].z, d[j].w)));
#pragma unroll
    for (int off = 1; off < 64; off <<= 1)
        M = fmaxf(M, __shfl_xor(M, off, 64));

    if ((t & 63) == 0) wmax[gb * 4 + (t >> 6)] = M;   // wave-chunk max
}

// K2: one block per row. T = 5th-largest of the row's 128 wave-maxes. Since T
// is the min of 5 actual elements, V5(row) >= T, and every true top-5 element
// sits in a chunk with wmax >= T. Rescan only those (~5) chunks (LLC-resident),
// collect all elements >= T as u64 keys, exact top-5, scatter five 1.0 stores.
__global__ __launch_bounds__(TPB) void wta_finish(const float* __restrict__ x,
                                                  const float* __restrict__ wmax,
                                                  float* __restrict__ out) {
    const int row = blockIdx.x;
    const int t = threadIdx.x;
    const float* __restrict__ wm = wmax + row * WPR;

    __shared__ float sT;
    __shared__ int nflag, ncand;
    __shared__ int flaglist[NFLAG];
    __shared__ uint64_t cand[CAP];

    if (t == 0) { nflag = 0; ncand = 0; }
    __syncthreads();

    // ---- threshold: top-5 of 128 wave-maxes (first wave only) ----
    if (t < 64) {
        float v[K];
#pragma unroll
        for (int k = 0; k < K; ++k) v[k] = -INFINITY;
        insert5f(v, wm[t]);
        insert5f(v, wm[t + 64]);
#pragma unroll
        for (int off = 1; off < 64; off <<= 1) {
            float ov[K];
#pragma unroll
            for (int k = 0; k < K; ++k) ov[k] = __shfl_xor(v[k], off, 64);
#pragma unroll
            for (int k = 0; k < K; ++k) insert5f(v, ov[k]);
        }
        if (t == 0) sT = v[K - 1];
    }
    __syncthreads();
    const float T = sT;

    // ---- flag chunks with wmax >= T (expect ~5) ----
    if (t < WPR && wm[t] >= T) {
        const int s = atomicAdd(&nflag, 1);
        if (s < NFLAG) flaglist[s] = t;
    }
    __syncthreads();
    const int nf = min(nflag, NFLAG);

    // ---- rescan flagged chunks (coalesced, LLC-hot), collect survivors ----
    const int lane = t & 63, jj = t >> 6;
    for (int f = 0; f < nf; ++f) {
        const int wid = flaglist[f];
        const int gbk = wid >> 2;          // stream-block within row
        const int w   = wid & 3;           // wave within stream-block
        const float4* __restrict__ xb =
            (const float4*)(x + (size_t)row * NCOLS + (size_t)gbk * CHUNK);
#pragma unroll
        for (int rep = 0; rep < 2; ++rep) {
            const int j = jj + rep * 4;
            const int f4pos = w * 64 + lane + j * TPB;
            const float4 d = xb[f4pos];
            const float vs[4] = {d.x, d.y, d.z, d.w};
#pragma unroll
            for (int c = 0; c < 4; ++c) {
                if (vs[c] >= T) {
                    const int s = atomicAdd(&ncand, 1);
                    if (s < CAP)
                        cand[s] = make_key(vs[c],
                                           (uint32_t)gbk * CHUNK + (uint32_t)f4pos * 4u + c);
                }
            }
        }
    }
    __syncthreads();

    // ---- exact top-5 of survivors, scatter ones ----
    if (t < 64) {
        const int n = min(ncand, CAP);
        uint64_t key[K];
#pragma unroll
        for (int k = 0; k < K; ++k) key[k] = KEY_NEG_INF;
        for (int i = t; i < n; i += 64) insert5(key, cand[i]);
        wave_reduce5(key);
        if (t == 0) {
#pragma unroll
            for (int k = 0; k < K; ++k)
                if (key[k] != KEY_NEG_INF)
                    out[(size_t)row * NCOLS + key_idx(key[k])] = 1.0f;
        }
    }
}

extern "C" void kernel_launch(void* const* d_in, const int* in_sizes, int n_in,
                              void* d_out, int out_size, void* d_ws, size_t ws_size,
                              hipStream_t stream) {
    const float* x = (const float*)d_in[0];
    float* out = (float*)d_out;

    // ws layout: wmax (4096 * 4 f32 = 64 KiB)
    float* wmax = (float*)d_ws;

    wta_stream<<<BROWS * BPR, TPB, 0, stream>>>(x, out, wmax);
    wta_finish<<<BROWS, TPB, 0, stream>>>(x, wmax, out);
}